// Round 8
// baseline (174.206 us; speedup 1.0000x reference)
//
#include <hip/hip_runtime.h>
#include <stdint.h>

typedef unsigned long long u64;
typedef unsigned int u32;

#define FH 37
#define FW 62
#define NA 9
#define NPRED 20646        // FH*FW*NA
#define BS 4
#define KEEP_PRE 6000
#define KEEP_POST 300
#define NBINS 4096         // coarse: sign + 8-bit exp + 3 mantissa bits
#define SELCAP 3072        // ranks resolved per tranche
#define SLOTN 6144
#define FB_BASE 4608       // slots [FB_BASE, SLOTN) = fallback-bin region
#define NFB 640
#define NCHUNK 21          // ceil(20646/1024)
#define FSLOTS 32          // coarse bins covered by the fine map
#define FSUB 64            // fine sub-bins per coarse bin (bits [14:20))

// ---- LDS arena (bytes). Regions reused over time:
//  RG1: hist replicas (S1-S2) -> slots u64[6144] (T1-T5) -> cboxL float4[3072]
//  RG2: fineH/fineS/fineC (T1-T5) -> careaL f32[3072] (T6-)
#define L_HIST   0u        // u32[4096] coarse hist (merged)   persistent
#define L_SUF    16384u    // u32[4096] coarse suffix          persistent
#define L_RG1    32768u    // 48K
#define L_RG2    81920u    // 24K
#define L_FBCUR  106496u   // u32[640]
#define L_PERM   109056u   // u32[3072] rank -> element index
#define L_KBOX   121344u   // float4[304] kept boxes
#define L_KAREA  126208u   // f32[304]
#define L_WSUM   127424u   // u32[16]
#define L_WPOS   127488u   // u32[16]
#define L_SCAL   127552u   // 0:binLo 1:binHi 2:cnt 3:npos
#define L_AW     127616u   // u64[32] per-wave dead ballots (parity dbuf)
#define L_MROW   127872u   // u64[64] intra-block suppression rows
#define LDS_TOTAL 128384u

// ---------------------------------------------------------------------------
__device__ __forceinline__ u32 mapbits(float p) {
  u32 u = __float_as_uint(p);
  return (u & 0x80000000u) ? ~u : (u | 0x80000000u);   // order-preserving map
}
__device__ __forceinline__ u64 readlane64(u64 v, int srcLane) {
  u32 lo = __builtin_amdgcn_readlane((u32)v, srcLane);
  u32 hi = __builtin_amdgcn_readlane((u32)(v >> 32), srcLane);
  return ((u64)hi << 32) | lo;
}
// suppression test — textually identical op structure to rounds 0-6 (absmax=0)
__device__ __forceinline__ bool iou_sup(float kx1, float ky1, float kx2, float ky2,
                                        float ka, float cx1, float cy1,
                                        float cx2, float cy2, float ca) {
  float wx = fmaxf(fminf(kx2, cx2) - fmaxf(kx1, cx1), 0.f);
  float wy = fmaxf(fminf(ky2, cy2) - fmaxf(ky1, cy1), 0.f);
  float inter = wx * wy;
  float un = ka + ca - inter;
  return inter > 0.7f * fmaxf(un, 1e-9f);
}
// box decode — textually identical formula to rounds 0-6 (absmax=0)
__device__ __forceinline__ float4 decode_box(u32 n, float4 d, float W, float H) {
  int a = (int)(n % NA);
  int cell = (int)(n / NA);
  int x = cell % FW;
  int y = cell / FW;
  int si = a % 3, ri = a / 3;
  float s = (si==0) ? 8.f : ((si==1) ? 16.f : 32.f);
  float r = (ri==0) ? 0.5f : ((ri==1) ? 1.0f : 2.0f);
  float aw = s * sqrtf(1.0f / r);
  float ah = s * sqrtf(r);
  float gx = (float)x * 16.f, gy = (float)y * 16.f;
  float x1d = gx - 0.5f*aw, x2d = gx + 0.5f*aw;
  float y1d = gy - 0.5f*ah, y2d = gy + 0.5f*ah;
  float w = x2d - x1d, h = y2d - y1d;
  float cx = x1d + 0.5f*w, cy = y1d + 0.5f*h;
  float pcx = d.x*w + cx, pcy = d.y*h + cy;
  float pw = expf(d.z)*w, ph = expf(d.w)*h;
  float bx1 = fminf(fmaxf(pcx - 0.5f*pw, 0.f), W);
  float by1 = fminf(fmaxf(pcy - 0.5f*ph, 0.f), H);
  float bx2 = fminf(fmaxf(pcx + 0.5f*pw, 0.f), W);
  float by2 = fminf(fmaxf(pcy + 0.5f*ph, 0.f), H);
  return make_float4(bx1, by1, bx2, by2);
}

// ---------------------------------------------------------------------------
__global__ void __launch_bounds__(1024) detect_kernel(
    const float* __restrict__ preds, const float4* __restrict__ regs4,
    const int* __restrict__ ih, const int* __restrict__ iw,
    float4* __restrict__ out)
{
  __shared__ __align__(16) char smem[LDS_TOTAL];
  u32*    histL  = (u32*)(smem + L_HIST);
  u32*    sufL   = (u32*)(smem + L_SUF);
  u32*    repl   = (u32*)(smem + L_RG1);          // 3 x 4096 replicas
  u64*    slots  = (u64*)(smem + L_RG1);
  float4* cboxL  = (float4*)(smem + L_RG1);
  u32*    fineH  = (u32*)(smem + L_RG2);
  u32*    fineS  = (u32*)(smem + L_RG2 + 8192);
  u32*    fineC  = (u32*)(smem + L_RG2 + 16384);
  float*  careaL = (float*)(smem + L_RG2);
  u32*    fbCur  = (u32*)(smem + L_FBCUR);
  u32*    perm   = (u32*)(smem + L_PERM);
  float4* kbox   = (float4*)(smem + L_KBOX);
  float*  karea  = (float*)(smem + L_KAREA);
  u32*    wsum   = (u32*)(smem + L_WSUM);
  u32*    wpos   = (u32*)(smem + L_WPOS);
  u32*    scal   = (u32*)(smem + L_SCAL);
  u64*    aw     = (u64*)(smem + L_AW);
  u64*    mrow   = (u64*)(smem + L_MROW);

  const int b = blockIdx.x;
  const int t = threadIdx.x;
  const int lane = t & 63;
  const int wv = t >> 6;
  const float* pb = preds + b*NPRED;
  const float4* rb = regs4 + b*NPRED;
  const float W = (float)(*iw), H = (float)(*ih);
  float4* ob = out + b*KEEP_POST;
  const float4 zero = make_float4(0.f, 0.f, 0.f, 0.f);

  // ---- S0: zero hist + replicas ------------------------------------------
  #pragma unroll
  for (int q = 0; q < 4; ++q) histL[q*1024 + t] = 0;
  #pragma unroll
  for (int q = 0; q < 12; ++q) repl[q*1024 + t] = 0;
  if (t == 0) scal[2] = 0;
  __syncthreads();

  // ---- S1: coarse hist into per-wave-group replica + npos -----------------
  {
    u32* repA = ((wv & 3) == 0) ? histL : (repl + ((wv & 3) - 1) * 4096);
    u32 mypos = 0;
    #pragma unroll 4
    for (int c = 0; c < NCHUNK; ++c) {
      int n = c*1024 + t;
      bool valid = (n < NPRED);
      float p = valid ? pb[n] : -1.0f;
      u64 bm = __ballot(valid && (p > 0.0f));
      mypos += (u32)__popcll(bm);
      if (valid) atomicAdd(&repA[mapbits(p) >> 20], 1u);
    }
    if (lane == 0) wpos[wv] = mypos;
  }
  __syncthreads();

  // ---- S2: merge replicas + coarse suffix scan ----------------------------
  {
    u32* r2 = repl + 4096; u32* r3 = repl + 8192;
    u32 h0 = histL[4*t+0] + repl[4*t+0] + r2[4*t+0] + r3[4*t+0];
    u32 h1 = histL[4*t+1] + repl[4*t+1] + r2[4*t+1] + r3[4*t+1];
    u32 h2 = histL[4*t+2] + repl[4*t+2] + r2[4*t+2] + r3[4*t+2];
    u32 h3 = histL[4*t+3] + repl[4*t+3] + r2[4*t+3] + r3[4*t+3];
    histL[4*t+0]=h0; histL[4*t+1]=h1; histL[4*t+2]=h2; histL[4*t+3]=h3;
    u32 s = h0 + h1 + h2 + h3;
    u32 sf = s;
    #pragma unroll
    for (int off = 1; off < 64; off <<= 1) {
      u32 o = __shfl_down(sf, off, 64);
      if (lane + off < 64) sf += o;
    }
    if (lane == 0) wsum[wv] = sf;
    __syncthreads();
    u32 hi = 0;
    #pragma unroll
    for (int w2 = 0; w2 < 16; ++w2) hi += (w2 > wv) ? wsum[w2] : 0u;
    u32 St = hi + (sf - s);
    u32 s3 = St, s2 = s3 + h3, s1 = s2 + h2, s0 = s1 + h1;
    sufL[4*t+0]=s0; sufL[4*t+1]=s1; sufL[4*t+2]=s2; sufL[4*t+3]=s3;
    if (t == 0) {
      u32 np = 0;
      #pragma unroll
      for (int w2 = 0; w2 < 16; ++w2) np += wpos[w2];
      scal[3] = np;
    }
  }
  __syncthreads();

  // ---- tranche loop (tranche 1 runs only if NMS starves before 300) ------
  #pragma unroll 1
  for (int tr = 0; tr < 2; ++tr) {
    const u32 winStart = (u32)tr * SELCAP;
    const u32 winEnd = winStart + SELCAP;
    const int rowLimit = (KEEP_PRE - (int)winStart < (int)SELCAP)
                           ? (KEEP_PRE - (int)winStart) : (int)SELCAP;

    if (t == 0) { scal[0] = 0xFFFFFFFFu; scal[1] = 0u; }
    __syncthreads();
    #pragma unroll
    for (int q = 0; q < 4; ++q) {
      int v = 4*t + q;
      u32 hv = histL[v], sv = sufL[v];
      if (hv && sv < winEnd && sv + hv > winStart) {
        atomicMin(&scal[0], (u32)v);
        atomicMax(&scal[1], (u32)v);
      }
    }
    __syncthreads();
    const u32 binLo = scal[0], binHi = scal[1];
    u32 cBase = binLo;
    if (binHi - binLo >= FSLOTS) cBase = binHi - (FSLOTS - 1);
    const u32 S_top = sufL[binHi];                     // # in coarse bins > binHi
    const u32 S_cb = (cBase > 0) ? sufL[cBase-1] : 0;  // # in bins >= cBase
    const u32 rebWinEnd = winEnd - S_top;

    // ---- T1: init fine arrays + slots + fallback cursors ------------------
    #pragma unroll
    for (int q = 0; q < 2; ++q) fineH[q*1024 + t] = 0;
    #pragma unroll
    for (int q = 0; q < 6; ++q) slots[q*1024 + t] = 0ull;
    if (t < NFB) {
      u32 v = binLo + (u32)t;
      fbCur[t] = (v < cBase) ? (FB_BASE + (sufL[v] - S_cb)) : (u32)SLOTN;
    }
    __syncthreads();

    // ---- T2: fine histogram over top-FSLOTS window coarse bins ------------
    #pragma unroll 4
    for (int c = 0; c < NCHUNK; ++c) {
      int n = c*1024 + t;
      if (n < NPRED) {
        u32 m = mapbits(pb[n]);
        u32 cb = m >> 20;
        if (cb >= cBase && cb <= binHi)
          atomicAdd(&fineH[((cb - cBase) << 6) | ((m >> 14) & 0x3F)], 1u);
      }
    }
    __syncthreads();

    // ---- T3: fine suffix scan (2048 bins, 2/thread) -----------------------
    {
      u32 f0 = fineH[2*t], f1 = fineH[2*t+1];
      u32 s = f0 + f1;
      u32 sf = s;
      #pragma unroll
      for (int off = 1; off < 64; off <<= 1) {
        u32 o = __shfl_down(sf, off, 64);
        if (lane + off < 64) sf += o;
      }
      if (lane == 0) wsum[wv] = sf;
      __syncthreads();
      u32 hi = 0;
      #pragma unroll
      for (int w2 = 0; w2 < 16; ++w2) hi += (w2 > wv) ? wsum[w2] : 0u;
      u32 St = hi + (sf - s);
      u32 sA = St + f1, sB = St;
      fineS[2*t] = sA; fineS[2*t+1] = sB;
      fineC[2*t] = sA; fineC[2*t+1] = sB;
    }
    __syncthreads();

    // ---- T4: scatter keys into slots (fine region + fallback region) -----
    #pragma unroll 4
    for (int c = 0; c < NCHUNK; ++c) {
      int n = c*1024 + t;
      if (n < NPRED) {
        u32 m = mapbits(pb[n]);
        u32 cb = m >> 20;
        u64 key = ((u64)m << 32) | (u32)(~(u32)n);
        if (cb >= cBase && cb <= binHi) {
          u32 F = ((cb - cBase) << 6) | ((m >> 14) & 0x3F);
          if (fineS[F] < rebWinEnd) {
            u32 pos = atomicAdd(&fineC[F], 1u);
            if (pos < FB_BASE) slots[pos] = key;
          }
        } else if (cb >= binLo && cb < cBase) {
          u32 fo = cb - binLo;
          if (fo < NFB) {
            u32 pos = atomicAdd(&fbCur[fo], 1u);
            if (pos < SLOTN) slots[pos] = key;
          }
        }
      }
    }
    __syncthreads();

    // ---- T5: exact rank -> perm[local rank] (4-wide independent loads) ----
    #pragma unroll
    for (int q = 0; q < 6; ++q) {
      int i = q*1024 + t;
      u64 k = slots[i];
      if (k != 0) {
        u32 m = (u32)(k >> 32);
        u32 cb = m >> 20;
        u32 base, end, rbase;
        if (cb >= cBase) {
          u32 F = ((cb - cBase) << 6) | ((m >> 14) & 0x3F);
          base = fineS[F];
          end = base + fineH[F]; if (end > FB_BASE) end = FB_BASE;
          rbase = S_top + fineS[F];
        } else {
          base = FB_BASE + (sufL[cb] - S_cb);
          end = base + histL[cb]; if (end > SLOTN) end = SLOTN;
          rbase = sufL[cb];
        }
        u32 c2 = 0;
        for (u32 j = base; j < end; j += 4) {
          u64 s0 = slots[j];
          u64 s1 = (j+1 < end) ? slots[j+1] : 0ull;
          u64 s2 = (j+2 < end) ? slots[j+2] : 0ull;
          u64 s3 = (j+3 < end) ? slots[j+3] : 0ull;
          c2 += (u32)(s0 > k) + (u32)(s1 > k) + (u32)(s2 > k) + (u32)(s3 > k);
        }
        int local = (int)(rbase + c2) - (int)winStart;
        if (local >= 0 && local < rowLimit) perm[local] = ~(u32)k;
      }
    }
    __syncthreads();

    // ---- T6: decode window boxes + areas into LDS (overlays slots/fine) ---
    for (int r = t; r < rowLimit; r += 1024) {
      u32 idx = perm[r];
      float4 bx = decode_box(idx, rb[idx], W, H);
      cboxL[r] = bx;
      careaL[r] = (bx.z - bx.x) * (bx.w - bx.y);
    }
    __syncthreads();

    // ---- T7: greedy NMS. Phase A by 16 waves; mask+closure only if needed -
    {
      const int npos = (int)scal[3];
      const int nblk = (rowLimit + 63) >> 6;
      for (int blk = 0; blk < nblk; ++blk) {
        int cnt = (int)scal[2];          // uniform (post-barrier)
        if (cnt >= KEEP_POST) break;
        const int base = blk * 64;
        const int ci = base + lane;
        const bool valid = (ci < rowLimit);
        float4 cur = cboxL[valid ? ci : 0];
        float carea = careaL[valid ? ci : 0];

        // Phase A: kept-list check, kept indices strided across 16 waves
        int dead = 0;
        #pragma unroll 2
        for (int k = wv; k < cnt; k += 16) {
          float4 kb = kbox[k];
          dead |= (int)iou_sup(kb.x, kb.y, kb.z, kb.w, karea[k],
                               cur.x, cur.y, cur.z, cur.w, carea);
        }
        u64* awb = aw + ((blk & 1) << 4);   // parity dbuf (A==0 fast path safe)
        awb[wv] = __ballot(dead);
        __syncthreads();

        // all waves compute identical A
        u64 deadAll = 0;
        #pragma unroll
        for (int k = 0; k < 16; ++k) deadAll |= awb[k];
        int rem = rowLimit - base;
        u64 vm = (rem >= 64) ? ~0ull : ((1ull << rem) - 1ull);
        u64 A = vm & ~deadAll;
        if (A == 0) continue;            // nothing survives: 1 barrier total

        // intra-block 64x64 suppression rows, 4 rows per wave, only live rows
        #pragma unroll
        for (int q = 0; q < 4; ++q) {
          int j = wv*4 + q;
          if ((A >> j) & 1ull) {         // uniform branch (A uniform)
            float4 bj = cboxL[base + j];
            float ja = careaL[base + j];
            bool s = iou_sup(bj.x, bj.y, bj.z, bj.w, ja,
                             cur.x, cur.y, cur.z, cur.w, carea);
            u64 bm = __ballot(s);
            if (lane == 0) mrow[j] = bm;
          } else if (lane == 0) {
            mrow[j] = 0ull;
          }
        }
        __syncthreads();

        // closure: wave 0 bit-sweep; mask rows live in registers (lane l
        // holds mrow[l]); per-keep chain = ctz + 2 readlanes + bit ops.
        if (wv == 0) {
          u64 mreg = mrow[lane];         // one ds_read_b64 per lane
          int c2 = cnt;
          while (A && c2 < KEEP_POST) {
            int j = (int)__builtin_ctzll(A);
            A &= A - 1;
            A &= ~readlane64(mreg, j);   // j's victims (bits > j)
            if (lane == 0) {
              float4 bj = cboxL[base + j];
              kbox[c2] = bj;
              karea[c2] = careaL[base + j];
              ob[c2] = ((int)(winStart + (u32)(base + j)) < npos) ? bj : zero;
            }
            ++c2;
          }
          if (lane == 0) scal[2] = (u32)c2;
        }
        __syncthreads();
      }
    }
    __syncthreads();                     // scal[2] visible to all waves
    if ((int)scal[2] >= KEEP_POST) break;
  }

  // ---- tail zero-fill (d_out is poisoned before every timed launch) ------
  for (int k2 = (int)scal[2] + t; k2 < KEEP_POST; k2 += 1024) ob[k2] = zero;
}

extern "C" void kernel_launch(void* const* d_in, const int* in_sizes, int n_in,
                              void* d_out, int out_size, void* d_ws, size_t ws_size,
                              hipStream_t stream) {
  const float* preds  = (const float*)d_in[0];
  const float4* regs4 = (const float4*)d_in[1];
  const int* ih       = (const int*)d_in[2];
  const int* iw       = (const int*)d_in[3];
  (void)d_ws; (void)ws_size; (void)in_sizes; (void)n_in; (void)out_size;

  detect_kernel<<<dim3(BS), 1024, 0, stream>>>(
      preds, regs4, ih, iw, (float4*)d_out);
}